// Round 4
// baseline (200.417 us; speedup 1.0000x reference)
//
#include <hip/hip_runtime.h>
#include <math.h>

// ConvBertLightConv: dynamic depthwise conv with softmax-normalized per-(pos,head) kernels.
// B=8, S=4096, D=768 (12 heads x 64), K=9, 'same' zero padding along S.
// out[b,s,h,d] = sum_k softmax(filters[b,s,h,:])[k] * x[b, s+k-4, h*64+d]
//
// R4 = R3 with the nontemporal-store type fixed: use a native ext_vector_type
// float4 (fvec4) instead of HIP_vector_type, which __builtin_nontemporal_store
// accepts. Sliding 9-row register window, named vars only (no arrays ->
// nothing can be scratch-demoted), one-row-ahead prefetch.

#define KS 9
#define HD 64
#define NH 12
#define DMODEL 768   // NH*HD
#define SEQ 4096
#define BATCH 8
#define TTILE 32     // s-positions per block
#define CHUNKS (SEQ / TTILE)   // 128

typedef float fvec4 __attribute__((ext_vector_type(4)));

__global__ __launch_bounds__(192, 4) void lightconv_kernel(
    const float* __restrict__ x,      // [B, S, 768]
    const float* __restrict__ filt,   // [B, S, 108]
    float* __restrict__ out)          // [B, S, 768]
{
    const int blk   = blockIdx.x;             // b * CHUNKS + chunk
    const int chunk = blk & (CHUNKS - 1);
    const int b     = blk >> 7;               // / CHUNKS
    const int s0    = chunk * TTILE;
    const int t     = threadIdx.x;            // 0..191
    const int head  = t >> 4;                 // 0..11
    const int d4    = (t & 15) << 2;          // 0,4,...,60

    const float* xc = x    + (size_t)b * SEQ * DMODEL + head * HD + d4;
    float*       oc = out  + (size_t)b * SEQ * DMODEL + head * HD + d4;
    const float* fc = filt + (size_t)b * SEQ * (NH * KS) + head * KS;

    const fvec4 zero = (fvec4)(0.f);

#define XROW(ss) (*reinterpret_cast<const fvec4*>(xc + (size_t)(ss) * DMODEL))

    // Preload the 9-row window for s = s0: rows s0-4 .. s0+4.
    // Upper bound always in range (s0+4 <= 4068); lower bound needs chunk-0 check.
    fvec4 w0 = (s0 - 4 >= 0) ? XROW(s0 - 4) : zero;
    fvec4 w1 = (s0 - 3 >= 0) ? XROW(s0 - 3) : zero;
    fvec4 w2 = (s0 - 2 >= 0) ? XROW(s0 - 2) : zero;
    fvec4 w3 = (s0 - 1 >= 0) ? XROW(s0 - 1) : zero;
    fvec4 w4 = XROW(s0 + 0);
    fvec4 w5 = XROW(s0 + 1);
    fvec4 w6 = XROW(s0 + 2);
    fvec4 w7 = XROW(s0 + 3);
    fvec4 w8 = XROW(s0 + 4);

#pragma unroll
    for (int i = 0; i < TTILE; ++i) {
        const int s = s0 + i;

        // prefetch next trailing row (needed at step i+1): row s+5
        fvec4 nxt = zero;
        if (i < TTILE - 1 && s + 5 < SEQ) nxt = XROW(s + 5);

        // softmax over the 9 taps for (b, s, head) — redundant across the 16
        // lanes of a head (same addresses -> one cacheline per wave-group).
        const float* fp = fc + (size_t)s * (NH * KS);
        const float f0 = fp[0], f1 = fp[1], f2 = fp[2], f3 = fp[3], f4 = fp[4];
        const float f5 = fp[5], f6 = fp[6], f7 = fp[7], f8 = fp[8];
        float m = fmaxf(f0, f1);
        m = fmaxf(m, f2); m = fmaxf(m, f3); m = fmaxf(m, f4);
        m = fmaxf(m, f5); m = fmaxf(m, f6); m = fmaxf(m, f7); m = fmaxf(m, f8);
        const float e0 = __expf(f0 - m), e1 = __expf(f1 - m), e2 = __expf(f2 - m);
        const float e3 = __expf(f3 - m), e4 = __expf(f4 - m), e5 = __expf(f5 - m);
        const float e6 = __expf(f6 - m), e7 = __expf(f7 - m), e8 = __expf(f8 - m);
        const float inv = 1.0f / (((e0 + e1) + (e2 + e3)) + (((e4 + e5) + (e6 + e7)) + e8));

        fvec4 acc = e0 * w0;
        acc += e1 * w1;
        acc += e2 * w2;
        acc += e3 * w3;
        acc += e4 * w4;
        acc += e5 * w5;
        acc += e6 * w6;
        acc += e7 * w7;
        acc += e8 * w8;
        acc *= inv;

        __builtin_nontemporal_store(acc, reinterpret_cast<fvec4*>(oc + (size_t)s * DMODEL));

        // rotate window (pure SSA renaming after unroll; no arrays anywhere)
        w0 = w1; w1 = w2; w2 = w3; w3 = w4; w4 = w5; w5 = w6; w6 = w7; w7 = w8; w8 = nxt;
    }
#undef XROW
}

extern "C" void kernel_launch(void* const* d_in, const int* in_sizes, int n_in,
                              void* d_out, int out_size, void* d_ws, size_t ws_size,
                              hipStream_t stream) {
    const float* x    = (const float*)d_in[0];   // [8,4096,768] fp32
    const float* filt = (const float*)d_in[1];   // [8,4096,108] fp32
    float* out        = (float*)d_out;           // [8,4096,12,64] fp32

    const int grid = BATCH * CHUNKS;             // 1024 blocks
    lightconv_kernel<<<grid, 192, 0, stream>>>(x, filt, out);
}

// Round 5
// 199.512 us; speedup vs baseline: 1.0045x; 1.0045x over previous
//
#include <hip/hip_runtime.h>
#include <math.h>

// ConvBertLightConv: dynamic depthwise conv with softmax-normalized per-(pos,head) kernels.
// B=8, S=4096, D=768 (12 heads x 64), K=9, 'same' zero padding along S.
// out[b,s,h,d] = sum_k softmax(filters[b,s,h,:])[k] * x[b, s+k-4, h*64+d]
//
// R5 = R4 with TTILE 32 -> 16. R4's counters: FETCH 70 MB (near-ideal, L3
// absorbs halo), WRITE 98 MB, but OccupancyPercent=28% (1024 blocks x 3 waves
// = 3072 of 8192 wave slots) -> latency-bound by grid starvation. TTILE=16
// doubles the grid to 2048 blocks (75% occupancy cap); the extra halo reads
// (1.5x vs 1.25x) are L2/L3 hits.

#define KS 9
#define HD 64
#define NH 12
#define DMODEL 768   // NH*HD
#define SEQ 4096
#define BATCH 8
#define TTILE 16     // s-positions per block
#define CHUNKS (SEQ / TTILE)   // 256

typedef float fvec4 __attribute__((ext_vector_type(4)));

__global__ __launch_bounds__(192, 4) void lightconv_kernel(
    const float* __restrict__ x,      // [B, S, 768]
    const float* __restrict__ filt,   // [B, S, 108]
    float* __restrict__ out)          // [B, S, 768]
{
    const int blk   = blockIdx.x;             // b * CHUNKS + chunk
    const int chunk = blk & (CHUNKS - 1);
    const int b     = blk >> 8;               // / CHUNKS
    const int s0    = chunk * TTILE;
    const int t     = threadIdx.x;            // 0..191
    const int head  = t >> 4;                 // 0..11
    const int d4    = (t & 15) << 2;          // 0,4,...,60

    const float* xc = x    + (size_t)b * SEQ * DMODEL + head * HD + d4;
    float*       oc = out  + (size_t)b * SEQ * DMODEL + head * HD + d4;
    const float* fc = filt + (size_t)b * SEQ * (NH * KS) + head * KS;

    const fvec4 zero = (fvec4)(0.f);

#define XROW(ss) (*reinterpret_cast<const fvec4*>(xc + (size_t)(ss) * DMODEL))

    // Preload the 9-row window for s = s0: rows s0-4 .. s0+4.
    // Upper bound always in range (s0+4 <= SEQ-TTILE+4); lower bound needs chunk-0 check.
    fvec4 w0 = (s0 - 4 >= 0) ? XROW(s0 - 4) : zero;
    fvec4 w1 = (s0 - 3 >= 0) ? XROW(s0 - 3) : zero;
    fvec4 w2 = (s0 - 2 >= 0) ? XROW(s0 - 2) : zero;
    fvec4 w3 = (s0 - 1 >= 0) ? XROW(s0 - 1) : zero;
    fvec4 w4 = XROW(s0 + 0);
    fvec4 w5 = XROW(s0 + 1);
    fvec4 w6 = XROW(s0 + 2);
    fvec4 w7 = XROW(s0 + 3);
    fvec4 w8 = XROW(s0 + 4);

#pragma unroll
    for (int i = 0; i < TTILE; ++i) {
        const int s = s0 + i;

        // prefetch next trailing row (needed at step i+1): row s+5
        fvec4 nxt = zero;
        if (i < TTILE - 1 && s + 5 < SEQ) nxt = XROW(s + 5);

        // softmax over the 9 taps for (b, s, head) — redundant across the 16
        // lanes of a head (same addresses -> broadcast-served).
        const float* fp = fc + (size_t)s * (NH * KS);
        const float f0 = fp[0], f1 = fp[1], f2 = fp[2], f3 = fp[3], f4 = fp[4];
        const float f5 = fp[5], f6 = fp[6], f7 = fp[7], f8 = fp[8];
        float m = fmaxf(f0, f1);
        m = fmaxf(m, f2); m = fmaxf(m, f3); m = fmaxf(m, f4);
        m = fmaxf(m, f5); m = fmaxf(m, f6); m = fmaxf(m, f7); m = fmaxf(m, f8);
        const float e0 = __expf(f0 - m), e1 = __expf(f1 - m), e2 = __expf(f2 - m);
        const float e3 = __expf(f3 - m), e4 = __expf(f4 - m), e5 = __expf(f5 - m);
        const float e6 = __expf(f6 - m), e7 = __expf(f7 - m), e8 = __expf(f8 - m);
        const float inv = 1.0f / (((e0 + e1) + (e2 + e3)) + (((e4 + e5) + (e6 + e7)) + e8));

        fvec4 acc = e0 * w0;
        acc += e1 * w1;
        acc += e2 * w2;
        acc += e3 * w3;
        acc += e4 * w4;
        acc += e5 * w5;
        acc += e6 * w6;
        acc += e7 * w7;
        acc += e8 * w8;
        acc *= inv;

        __builtin_nontemporal_store(acc, reinterpret_cast<fvec4*>(oc + (size_t)s * DMODEL));

        // rotate window (pure SSA renaming after unroll; no arrays anywhere)
        w0 = w1; w1 = w2; w2 = w3; w3 = w4; w4 = w5; w5 = w6; w6 = w7; w7 = w8; w8 = nxt;
    }
#undef XROW
}

extern "C" void kernel_launch(void* const* d_in, const int* in_sizes, int n_in,
                              void* d_out, int out_size, void* d_ws, size_t ws_size,
                              hipStream_t stream) {
    const float* x    = (const float*)d_in[0];   // [8,4096,768] fp32
    const float* filt = (const float*)d_in[1];   // [8,4096,108] fp32
    float* out        = (float*)d_out;           // [8,4096,12,64] fp32

    const int grid = BATCH * CHUNKS;             // 2048 blocks
    lightconv_kernel<<<grid, 192, 0, stream>>>(x, filt, out);
}